// Round 6
// baseline (263.294 us; speedup 1.0000x reference)
//
#include <hip/hip_runtime.h>
#include <hip/hip_bf16.h>

// (B, LIN, E, D, N) = (32, 2048, 512, 512, 2)
#define L_SZ 2048
#define E_SZ 512
#define D_SZ 512
#define ND   1024
// ws: dec (32*512 f32 = 64 KB) | Bt (512*512 bf16 = 512 KB, [n][k]) | spart (2*32*2048 f32 = 512 KB)
#define WS_DEC_OFF 0
#define WS_BT_OFF  65536
#define WS_SP_OFF  (65536 + 524288)

typedef unsigned short ushort_t;
typedef unsigned int   uint_t;
typedef __attribute__((ext_vector_type(8))) short short8;   // 8 bf16 (MFMA A/B frag)
typedef __attribute__((ext_vector_type(4))) float floatx4;  // MFMA C/D frag

__device__ __forceinline__ ushort_t f2bf(float f) {
  uint_t u = __builtin_bit_cast(uint_t, f);
  u += 0x7fffu + ((u >> 16) & 1u);
  return (ushort_t)(u >> 16);
}

__device__ __forceinline__ float fast_tanh(float x) {
  float e = __expf(2.0f * x);
  return 1.0f - 2.0f * __builtin_amdgcn_rcpf(e + 1.0f);
}

// async 16B/lane global->LDS DMA; lds dest wave-uniform, HW deposits lane i at +16i
__device__ __forceinline__ void dma16(const ushort_t* g, ushort_t* l) {
  __builtin_amdgcn_global_load_lds(
      (const __attribute__((address_space(1))) uint_t*)(const void*)g,
      (__attribute__((address_space(3))) uint_t*)(void*)l,
      16, 0, 0);
}

// ---------------------------------------------------------------------------
// Prep, 512 blocks:
//  0..255  : dec partial: block (b=blk>>3, kq=blk&7) does k-slice kq*128..+128,
//            full-width coalesced W1 reads, fp32 atomicAdd into zeroed dec.
//            (b1 is folded into main_k's epilogue.)
//  256..511: Bt[n][k] = bf16(W1[1024+k][n]) via 32x32 LDS transpose (round-5 proven)
// ---------------------------------------------------------------------------
__global__ __launch_bounds__(256) void prep_k(const float* __restrict__ dh,
                                              const float* __restrict__ W1,
                                              float* __restrict__ dec,
                                              ushort_t* __restrict__ Bt) {
  int blk = blockIdx.x, t = threadIdx.x;
  if (blk < 256) {
    int b = blk >> 3, kq = blk & 7;
    __shared__ float sdf[128];
    if (t < 128) sdf[t] = dh[b * ND + kq * 128 + t];
    __syncthreads();
    const float* wrow = W1 + (size_t)kq * 128 * D_SZ;
    int d0 = t, d1 = t + 256;
    float s0 = 0.f, s1 = 0.f;
    #pragma unroll 4
    for (int k = 0; k < 128; k++) {
      float dv = sdf[k];
      s0 = fmaf(dv, wrow[k * D_SZ + d0], s0);
      s1 = fmaf(dv, wrow[k * D_SZ + d1], s1);
    }
    atomicAdd(&dec[b * D_SZ + d0], s0);
    atomicAdd(&dec[b * D_SZ + d1], s1);
  } else {
    int tid = blk - 256;
    int tk = (tid >> 4) * 32, tn = (tid & 15) * 32;
    __shared__ float tile[32][33];
    int cc = t & 31, r8 = t >> 5;
    #pragma unroll
    for (int p = 0; p < 4; p++) {
      int r = r8 + p * 8;
      tile[r][cc] = W1[(ND + tk + r) * D_SZ + tn + cc];
    }
    __syncthreads();
    #pragma unroll
    for (int p = 0; p < 4; p++) {
      int nn = r8 + p * 8;
      Bt[(tn + nn) * E_SZ + tk + cc] = f2bf(tile[cc][nn]);
    }
  }
}

// ---------------------------------------------------------------------------
// Main: B-IN-REGISTERS GEMM. WG = 512 thr (8 waves); wave owns 32 cols
// (cg*256 + wave*32), ALL K=512 as 16 k-steps: bf[2][16] short8 = 128 VGPRs,
// loaded ONCE in a prologue (4 rounds of round-5-proven DMA+XOR staging into
// the A-LDS area used as scratch). Steady state stages ONLY A:
// 4 l-tiles x 2 K-windows(256); per step: cvt prefetched regs -> ds_write
// As[win] -> barrier (lgkm drain only, no DMA) -> issue next A loads (consumed
// after next barrier, round-5-proven shape) -> 8 ks x 4mt x 2nt MFMA with B
// from regs -> barrier. Per-tile epilogue: tanh(acc+dec+b1).w2 -> spart[cg].
// LDS: 2 x 32 KB A ping-pong (= 64 KB B-prologue scratch) + s_sc. 1 WG/CU
// (2 waves/SIMD at ~250 VGPR). A re-read x2 (cg halves) is L3-absorbed
// (round-5 FETCH evidence). Total staged traffic/CU ~1.5 MB vs round 5's 2.5.
// ---------------------------------------------------------------------------
__global__ __launch_bounds__(512, 2) void main_k(const float* __restrict__ enc,
                                                 const ushort_t* __restrict__ Bt,
                                                 const float* __restrict__ dec,
                                                 const float* __restrict__ b1,
                                                 const float* __restrict__ w2,
                                                 float* __restrict__ spart) {
  const int lslot = blockIdx.x;          // 8 slots x 4 tiles = 32 l-tiles
  const int b     = blockIdx.y;
  const int cg    = blockIdx.z;          // column group: cols cg*256..+255
  const int t     = threadIdx.x;         // 0..511
  const int wave  = t >> 6, lane = t & 63;
  const int col   = lane & 15, quad = lane >> 4;

  __shared__ ushort_t lds[2][64 * 256];  // 2 x 32 KB A buffers (= 64 KB B scratch)
  __shared__ float s_sc[64];

  // ---- A geometry: thread owns row m=t>>3, k-chunk ac=t&7; per window loads
  //      4 chunks (j*64 + ac*8, j<4) = 32 floats = pa[8] float4 ----
  const int m = t >> 3, ac = t & 7;
  const float* arow0 = enc + (size_t)(b * L_SZ + lslot * 256 + m) * E_SZ + ac * 8;

  // ---- issue A loads for (tile0, win0) first: HBM latency hides under B prologue ----
  float4 pa[8];
  #pragma unroll
  for (int j = 0; j < 4; j++) {
    pa[2 * j]     = *(const float4*)(arow0 + j * 64);
    pa[2 * j + 1] = *(const float4*)(arow0 + j * 64 + 4);
  }

  // ---- B prologue: 4 rounds of 256 rows x 128 k staged into lds (64 KB),
  //      frags pulled to registers. Round-5-proven DMA slot/swizzle math:
  //      slot s = wave*512 + j*64 + lane -> row n=s>>4, pos=s&15,
  //      src chunk c = pos ^ (n&7)  => logical chunk q lands at pos q^(n&7). ----
  short8 bf[2][16];
  {
    ushort_t* Bsc = &lds[0][0];
    const ushort_t* btc = Bt + (size_t)cg * 256 * E_SZ;
    #pragma unroll
    for (int R = 0; R < 4; R++) {
      #pragma unroll
      for (int j = 0; j < 8; j++) {
        int n = wave * 32 + j * 4 + (lane >> 4);
        int c = (lane & 15) ^ (n & 7);
        dma16(btc + (size_t)n * E_SZ + R * 128 + c * 8,
              &Bsc[(wave * 512 + j * 64) * 8]);
      }
      __syncthreads();   // drain DMA (vmcnt)
      #pragma unroll
      for (int nt = 0; nt < 2; nt++) {
        int n = wave * 32 + nt * 16 + col;
        #pragma unroll
        for (int ksr = 0; ksr < 4; ksr++)
          bf[nt][R * 4 + ksr] =
              *(const short8*)&Bsc[n * 128 + (((ksr * 4 + quad) ^ (n & 7)) << 3)];
      }
      __syncthreads();   // seal readers before next round overwrites
    }
  }

  floatx4 acc[4][2];

  #pragma unroll 1
  for (int tile = 0; tile < 4; tile++) {
    #pragma unroll
    for (int mt = 0; mt < 4; mt++)
      #pragma unroll
      for (int nt = 0; nt < 2; nt++)
        acc[mt][nt] = (floatx4){0.f, 0.f, 0.f, 0.f};

    #pragma unroll
    for (int win = 0; win < 2; win++) {
      // ---- cvt prefetched A regs -> ds_write into As[win] (4 x b128) ----
      #pragma unroll
      for (int j = 0; j < 4; j++) {
        union { short8 v; __hip_bfloat162 h[4]; } pk;
        float4 f0 = pa[2 * j], f1 = pa[2 * j + 1];
        pk.h[0] = __float22bfloat162_rn(make_float2(f0.x, f0.y));
        pk.h[1] = __float22bfloat162_rn(make_float2(f0.z, f0.w));
        pk.h[2] = __float22bfloat162_rn(make_float2(f1.x, f1.y));
        pk.h[3] = __float22bfloat162_rn(make_float2(f1.z, f1.w));
        *(short8*)&lds[win][m * 256 + ((j * 8 + (ac ^ (m & 7))) << 3)] = pk.v;
      }
      __syncthreads();   // barrier A: drains ds_writes (lgkm only — cheap)
      // ---- issue A loads for next step (consumed after next barrier A) ----
      {
        int lt = (win == 0) ? tile : tile + 1;
        int lw = win ^ 1;
        if (lt < 4) {
          const float* ap = arow0 + (size_t)lt * 64 * E_SZ + lw * 256;
          #pragma unroll
          for (int j = 0; j < 4; j++) {
            pa[2 * j]     = *(const float4*)(ap + j * 64);
            pa[2 * j + 1] = *(const float4*)(ap + j * 64 + 4);
          }
        }
      }
      // ---- MFMA: 8 k-steps of 32, A from LDS, B from registers ----
      #pragma unroll
      for (int ks = 0; ks < 8; ks++) {
        short8 af[4];
        #pragma unroll
        for (int mt = 0; mt < 4; mt++) {
          int mm = mt * 16 + col;
          af[mt] = *(const short8*)&lds[win][mm * 256 + (((ks * 4 + quad) ^ (mm & 7)) << 3)];
        }
        #pragma unroll
        for (int mt = 0; mt < 4; mt++)
          #pragma unroll
          for (int nt = 0; nt < 2; nt++)
            acc[mt][nt] = __builtin_amdgcn_mfma_f32_16x16x32_bf16(
                af[mt], bf[nt][win * 8 + ks], acc[mt][nt], 0, 0, 0);
      }
      __syncthreads();   // barrier B: seals readers of As[win] before reuse
    }

    // ---- per-tile epilogue: tanh(acc + dec + b1) . w2, reduce over 512 cols ----
    // C/D: row = quad*4+r -> global m = mt*16+quad*4+r; col -> n
    const int l0 = lslot * 256 + tile * 64;
    float sums[4][4];
    #pragma unroll
    for (int mt = 0; mt < 4; mt++)
      #pragma unroll
      for (int r = 0; r < 4; r++) sums[mt][r] = 0.f;
    #pragma unroll
    for (int nt = 0; nt < 2; nt++) {
      int n = cg * 256 + wave * 32 + nt * 16 + col;
      float dv = dec[b * D_SZ + n] + b1[n];
      float wv = w2[n];
      #pragma unroll
      for (int mt = 0; mt < 4; mt++)
        #pragma unroll
        for (int r = 0; r < 4; r++)
          sums[mt][r] += fast_tanh(acc[mt][nt][r] + dv) * wv;
    }
    if (t < 64) s_sc[t] = 0.f;
    __syncthreads();
    #pragma unroll
    for (int mt = 0; mt < 4; mt++) {
      #pragma unroll
      for (int r = 0; r < 4; r++) {
        float v = sums[mt][r];
        v += __shfl_xor(v, 1, 16);
        v += __shfl_xor(v, 2, 16);
        v += __shfl_xor(v, 4, 16);
        v += __shfl_xor(v, 8, 16);
        if (col == 0) atomicAdd(&s_sc[mt * 16 + quad * 4 + r], v);  // 8 waves/row
      }
    }
    __syncthreads();
    if (t < 64) spart[(size_t)cg * 32 * L_SZ + b * L_SZ + l0 + t] = s_sc[t];
    __syncthreads();   // s_sc reusable next tile
  }
}

// ---------------------------------------------------------------------------
// Softmax: one WG (1024 threads) per batch row; sums the two cg partials.
// ---------------------------------------------------------------------------
__global__ __launch_bounds__(1024) void softmax_k(const float* __restrict__ sp,
                                                  float* __restrict__ out) {
  int b = blockIdx.x, t = threadIdx.x;
  int wave = t >> 6, lane = t & 63;
  __shared__ float redm[16], reds[16];
  const float* r0 = sp + b * L_SZ;
  const float* r1 = sp + 32 * L_SZ + b * L_SZ;
  float v0 = r0[t] + r1[t];
  float v1 = r0[t + 1024] + r1[t + 1024];
  float mx = fmaxf(v0, v1);
  #pragma unroll
  for (int off = 32; off >= 1; off >>= 1) mx = fmaxf(mx, __shfl_xor(mx, off, 64));
  if (lane == 0) redm[wave] = mx;
  __syncthreads();
  float mm = redm[0];
  #pragma unroll
  for (int i = 1; i < 16; i++) mm = fmaxf(mm, redm[i]);
  v0 = __expf(v0 - mm);
  v1 = __expf(v1 - mm);
  float s = v0 + v1;
  #pragma unroll
  for (int off = 32; off >= 1; off >>= 1) s += __shfl_xor(s, off, 64);
  if (lane == 0) reds[wave] = s;
  __syncthreads();
  float sum = reds[0];
  #pragma unroll
  for (int i = 1; i < 16; i++) sum += reds[i];
  float inv = 1.0f / sum;
  out[b * L_SZ + t]        = v0 * inv;
  out[b * L_SZ + t + 1024] = v1 * inv;
}

extern "C" void kernel_launch(void* const* d_in, const int* in_sizes, int n_in,
                              void* d_out, int out_size, void* d_ws, size_t ws_size,
                              hipStream_t stream) {
  const float* d_hidden = (const float*)d_in[0];   // (32, 2, 512)
  const float* enc      = (const float*)d_in[1];   // (32, 2048, 512)
  const float* W1       = (const float*)d_in[2];   // (1536, 512)
  const float* b1       = (const float*)d_in[3];   // (512,)
  const float* w2       = (const float*)d_in[4];   // (512,)
  float* out = (float*)d_out;                      // (32, 2048)

  char* ws = (char*)d_ws;
  float*    dec = (float*)(ws + WS_DEC_OFF);
  ushort_t* Bt  = (ushort_t*)(ws + WS_BT_OFF);
  float*    sp  = (float*)(ws + WS_SP_OFF);

  hipMemsetAsync(dec, 0, 32 * D_SZ * sizeof(float), stream);  // atomic target
  prep_k<<<512, 256, 0, stream>>>(d_hidden, W1, dec, Bt);
  main_k<<<dim3(8, 32, 2), 512, 0, stream>>>(enc, Bt, dec, b1, w2, sp);
  softmax_k<<<32, 1024, 0, stream>>>(sp, out);
}